// Round 9
// baseline (377.709 us; speedup 1.0000x reference)
//
#include <hip/hip_runtime.h>
#include <hip/hip_fp16.h>

#define NA 100000
#define NE 300000
#define STEPS 4
#define NTILES (NE / 16)        // 18750 (exact)
#define ATILES (NA / 16)        // 6250  (exact)

typedef _Float16 f16;
typedef _Float16 half8 __attribute__((ext_vector_type(8)));
using f32x4  = __attribute__((ext_vector_type(4))) float;

// ---------------------------------------------------------------------------
// custom zero-fill
// ---------------------------------------------------------------------------
__global__ __launch_bounds__(256) void zero_kernel(float4* __restrict__ p, int n4)
{
    int t = blockIdx.x * 256 + threadIdx.x;
    if (t < n4) p[t] = make_float4(0.f, 0.f, 0.f, 0.f);
}

// ---------------------------------------------------------------------------
// fp32 -> fp16 bulk converts: h (step-0) and bond (once)
// ---------------------------------------------------------------------------
__global__ __launch_bounds__(256) void conv_kernel(
    const float* __restrict__ src, f16* __restrict__ dst, int n8)
{
    int t = blockIdx.x * 256 + threadIdx.x;   // one half8 (8 elems) per thread
    if (t >= n8) return;
    float4 a = reinterpret_cast<const float4*>(src)[2 * t];
    float4 b = reinterpret_cast<const float4*>(src)[2 * t + 1];
    half8 o;
    o[0]=(f16)a.x; o[1]=(f16)a.y; o[2]=(f16)a.z; o[3]=(f16)a.w;
    o[4]=(f16)b.x; o[5]=(f16)b.y; o[6]=(f16)b.z; o[7]=(f16)b.w;
    reinterpret_cast<half8*>(dst)[t] = o;
}

// ---------------------------------------------------------------------------
// Preconvert weights to fp16: Wbt[k][i][j] contiguous (k=16 is bias matrix),
// Wihb / Whhb = [96][32] row-major.
// ---------------------------------------------------------------------------
__global__ __launch_bounds__(256) void prep_kernel(
    const float* __restrict__ Wb, const float* __restrict__ bb,
    const float* __restrict__ Wih, const float* __restrict__ Whh,
    f16* __restrict__ Wbt, f16* __restrict__ Wihb, f16* __restrict__ Whhb)
{
    int t = blockIdx.x * 256 + threadIdx.x;     // < 17*32*32 + 2*96*32 = 23552
    if (t < 17 * 32 * 32) {
        int j = t & 31, i = (t >> 5) & 31, k = t >> 10;
        float v = (k < 16) ? Wb[k * 1024 + i * 32 + j] : bb[i * 32 + j];
        Wbt[t] = (f16)v;
    } else if (t < 17 * 32 * 32 + 3072) {
        int u = t - 17 * 32 * 32;
        Wihb[u] = (f16)Wih[u];
    } else if (t < 17 * 32 * 32 + 6144) {
        int u = t - 17 * 32 * 32 - 3072;
        Whhb[u] = (f16)Whh[u];
    }
}

// ---------------------------------------------------------------------------
// msg, swapped operands: D = W * (c.h). Lane (col,kg) holds msg[e=col][i=kg*4+r]
// (consecutive i!) -> dst is lane-local, outputs go out as packed-f16 atomics
// (global_atomic_pk_add_f16): 4 atomic instr/lane instead of 8 f32.
// ---------------------------------------------------------------------------
__global__ __launch_bounds__(256, 4) void msg_kernel(
    const f16* __restrict__ hb,              // [NA][32] fp16
    const f16* __restrict__ bondh,           // [NE][16] fp16
    const int* __restrict__ pair,            // [NE][2] (dst, nbr)
    const f16* __restrict__ Wbt,             // [17][32][32] fp16
    __half* __restrict__ agg)                // [NA][32] fp16, pre-zeroed
{
    int wave = threadIdx.x >> 6;
    int lane = threadIdx.x & 63;
    int tile = blockIdx.x * 4 + wave;
    if (tile >= NTILES) return;

    int col = lane & 15;         // edge slot within tile (B-col / D-col)
    int kg  = lane >> 4;         // k-group: j = kg*8..kg*8+7

    int e = tile * 16 + col;
    int2 p = reinterpret_cast<const int2*>(pair)[e];   // (dst, nbr) — lane-local

    half8 hf = *reinterpret_cast<const half8*>(hb + (size_t)p.y * 32 + kg * 8);
    half8 cA = *reinterpret_cast<const half8*>(bondh + (size_t)e * 16);
    half8 cB = *reinterpret_cast<const half8*>(bondh + (size_t)e * 16 + 8);

    f32x4 acc0 = {0.f, 0.f, 0.f, 0.f};      // i = kg*4 + r
    f32x4 acc1 = {0.f, 0.f, 0.f, 0.f};      // i = 16 + kg*4 + r

#pragma unroll
    for (int s = 0; s < 16; ++s) {
        half8 w0 = *reinterpret_cast<const half8*>(Wbt + (s * 32 + col) * 32 + kg * 8);
        half8 w1 = *reinterpret_cast<const half8*>(Wbt + (s * 32 + 16 + col) * 32 + kg * 8);
        f16 ch = (s < 8) ? cA[s] : cB[s - 8];
        half8 a = hf * ch;                   // v_pk_mul_f16 x4
        acc0 = __builtin_amdgcn_mfma_f32_16x16x32_f16(w0, a, acc0, 0, 0, 0);
        acc1 = __builtin_amdgcn_mfma_f32_16x16x32_f16(w1, a, acc1, 0, 0, 0);
    }
    {   // bias matrix (k=16): unscaled h
        half8 w0 = *reinterpret_cast<const half8*>(Wbt + (16 * 32 + col) * 32 + kg * 8);
        half8 w1 = *reinterpret_cast<const half8*>(Wbt + (16 * 32 + 16 + col) * 32 + kg * 8);
        acc0 = __builtin_amdgcn_mfma_f32_16x16x32_f16(w0, hf, acc0, 0, 0, 0);
        acc1 = __builtin_amdgcn_mfma_f32_16x16x32_f16(w1, hf, acc1, 0, 0, 0);
    }

    __half2* aggrow = reinterpret_cast<__half2*>(agg + (size_t)p.x * 32);
    unsafeAtomicAdd(&aggrow[kg * 2 + 0],     __float22half2_rn(make_float2(acc0[0], acc0[1])));
    unsafeAtomicAdd(&aggrow[kg * 2 + 1],     __float22half2_rn(make_float2(acc0[2], acc0[3])));
    unsafeAtomicAdd(&aggrow[8 + kg * 2 + 0], __float22half2_rn(make_float2(acc1[0], acc1[1])));
    unsafeAtomicAdd(&aggrow[8 + kg * 2 + 1], __float22half2_rn(make_float2(acc1[2], acc1[3])));
}

// ---------------------------------------------------------------------------
// GRU via MFMA (fp16). agg is fp16: xfrag is a single 16B load; agg re-zeroed
// in place for the next step. fp32 hout written only at the final step.
// ---------------------------------------------------------------------------
__global__ __launch_bounds__(256) void gru_kernel(
    f16* __restrict__ aggh,                   // [NA][32] fp16; zeroed on exit
    const f16* __restrict__ hb,               // [NA][32] fp16 (h_prev; rewritten)
    const f16* __restrict__ Wihb,             // [96][32] fp16
    const f16* __restrict__ Whhb,             // [96][32] fp16
    const float* __restrict__ bih, const float* __restrict__ bhh,
    float* __restrict__ hout, f16* __restrict__ hbf, int write_f32)
{
    int wave = threadIdx.x >> 6;
    int lane = threadIdx.x & 63;
    int tile = blockIdx.x * 4 + wave;
    if (tile >= ATILES) return;

    int base = tile * 16;
    int col  = lane & 15;
    int kg   = lane >> 4;

    half8* xp = reinterpret_cast<half8*>(aggh + (size_t)(base + col) * 32 + kg * 8);
    half8 xfrag = *xp;
    {
        half8 zz = {(f16)0, (f16)0, (f16)0, (f16)0, (f16)0, (f16)0, (f16)0, (f16)0};
        *xp = zz;                              // pre-zero agg for next step
    }
    half8 hfrag = *reinterpret_cast<const half8*>(hb + (size_t)(base + col) * 32 + kg * 8);

    f32x4 gi[6], gh[6];
#pragma unroll
    for (int t = 0; t < 6; ++t) {
        half8 bi = *reinterpret_cast<const half8*>(Wihb + (size_t)(t * 16 + col) * 32 + kg * 8);
        half8 bh = *reinterpret_cast<const half8*>(Whhb + (size_t)(t * 16 + col) * 32 + kg * 8);
        f32x4 z = {0.f, 0.f, 0.f, 0.f};
        gi[t] = __builtin_amdgcn_mfma_f32_16x16x32_f16(xfrag, bi, z, 0, 0, 0);
        gh[t] = __builtin_amdgcn_mfma_f32_16x16x32_f16(hfrag, bh, z, 0, 0, 0);
    }

#pragma unroll
    for (int hh = 0; hh < 2; ++hh) {
        int i  = hh * 16 + col;
        float br  = bih[i]      + bhh[i];
        float bz  = bih[32 + i] + bhh[32 + i];
        float bin = bih[64 + i];
        float bhn = bhh[64 + i];
#pragma unroll
        for (int reg = 0; reg < 4; ++reg) {
            int a = base + kg * 4 + reg;
            float r = 1.f / (1.f + __expf(-(gi[hh][reg] + gh[hh][reg] + br)));
            float z = 1.f / (1.f + __expf(-(gi[2 + hh][reg] + gh[2 + hh][reg] + bz)));
            float n = tanhf(gi[4 + hh][reg] + bin + r * (gh[4 + hh][reg] + bhn));
            float hp = (float)hb[(size_t)a * 32 + i];   // fp16 h_prev
            float o  = (1.f - z) * n + z * hp;
            if (write_f32) hout[(size_t)a * 32 + i] = o;
            hbf[(size_t)a * 32 + i] = (f16)o;
        }
    }
}

extern "C" void kernel_launch(void* const* d_in, const int* in_sizes, int n_in,
                              void* d_out, int out_size, void* d_ws, size_t ws_size,
                              hipStream_t stream)
{
    const float* atom = (const float*)d_in[0];
    const float* bond = (const float*)d_in[1];
    const int*   pair = (const int*)  d_in[2];
    const float* Wb   = (const float*)d_in[3];
    const float* bb   = (const float*)d_in[4];
    const float* W_ih = (const float*)d_in[5];
    const float* W_hh = (const float*)d_in[6];
    const float* b_ih = (const float*)d_in[7];
    const float* b_hh = (const float*)d_in[8];
    float* out = (float*)d_out;

    const size_t HBH = (size_t)NA * 32 * sizeof(f16);       // 6.4 MB
    __half* agg  = (__half*)d_ws;
    f16*   aggh  = (f16*)d_ws;
    f16*   hbf   = (f16*)((char*)d_ws + HBH);               // 6.4 MB
    f16*   bondh = (f16*)((char*)d_ws + 2 * HBH);           // 9.6 MB
    f16*   Wbt   = bondh + (size_t)NE * 16;                 // 34.8 KB
    f16*   Wihb  = Wbt + 17 * 32 * 32;
    f16*   Whhb  = Wihb + 96 * 32;

    const int zero_blocks  = (NA * 32 * 2 / 16 + 255) / 256;
    const int convh_blocks = (NA * 32 / 8 + 255) / 256;
    const int convb_blocks = (NE * 16 / 8 + 255) / 256;
    const int prep_blocks  = (17 * 32 * 32 + 6144 + 255) / 256;
    const int msg_blocks   = (NTILES + 3) / 4;
    const int gru_blocks   = (ATILES + 3) / 4;

    zero_kernel<<<zero_blocks, 256, 0, stream>>>((float4*)agg, NA * 32 * 2 / 16);
    prep_kernel<<<prep_blocks, 256, 0, stream>>>(Wb, bb, W_ih, W_hh, Wbt, Wihb, Whhb);
    conv_kernel<<<convh_blocks, 256, 0, stream>>>(atom, hbf, NA * 32 / 8);
    conv_kernel<<<convb_blocks, 256, 0, stream>>>(bond, bondh, NE * 16 / 8);

    for (int s = 0; s < STEPS; ++s) {
        msg_kernel<<<msg_blocks, 256, 0, stream>>>(hbf, bondh, pair, Wbt, agg);
        gru_kernel<<<gru_blocks, 256, 0, stream>>>(aggh, hbf, Wihb, Whhb,
                                                   b_ih, b_hh, out, hbf,
                                                   (s == STEPS - 1) ? 1 : 0);
    }
}

// Round 10
// 209.910 us; speedup vs baseline: 1.7994x; 1.7994x over previous
//
#include <hip/hip_runtime.h>

#define NA 100000
#define NE 300000
#define STEPS 4
#define NTILES (NE / 16)        // 18750 (exact)
#define ATILES (NA / 16)        // 6250  (exact)

typedef _Float16 f16;
typedef _Float16 half8 __attribute__((ext_vector_type(8)));
typedef _Float16 half4 __attribute__((ext_vector_type(4)));
using f32x4 = __attribute__((ext_vector_type(4))) float;

// ---------------------------------------------------------------------------
__global__ __launch_bounds__(256) void zero_kernel(float4* __restrict__ p, int n4)
{
    int t = blockIdx.x * 256 + threadIdx.x;
    if (t < n4) p[t] = make_float4(0.f, 0.f, 0.f, 0.f);
}

// fp32 -> fp16 bulk convert (step-0 h)
__global__ __launch_bounds__(256) void conv_kernel(
    const float* __restrict__ src, f16* __restrict__ dst, int n8)
{
    int t = blockIdx.x * 256 + threadIdx.x;
    if (t >= n8) return;
    float4 a = reinterpret_cast<const float4*>(src)[2 * t];
    float4 b = reinterpret_cast<const float4*>(src)[2 * t + 1];
    half8 o;
    o[0]=(f16)a.x; o[1]=(f16)a.y; o[2]=(f16)a.z; o[3]=(f16)a.w;
    o[4]=(f16)b.x; o[5]=(f16)b.y; o[6]=(f16)b.z; o[7]=(f16)b.w;
    reinterpret_cast<half8*>(dst)[t] = o;
}

// weights -> fp16 (Wbt[k][i][j], k=16 = bias matrix; Wihb/Whhb [96][32])
__global__ __launch_bounds__(256) void prep_kernel(
    const float* __restrict__ Wb, const float* __restrict__ bb,
    const float* __restrict__ Wih, const float* __restrict__ Whh,
    f16* __restrict__ Wbt, f16* __restrict__ Wihb, f16* __restrict__ Whhb)
{
    int t = blockIdx.x * 256 + threadIdx.x;
    if (t < 17 * 32 * 32) {
        int j = t & 31, i = (t >> 5) & 31, k = t >> 10;
        float v = (k < 16) ? Wb[k * 1024 + i * 32 + j] : bb[i * 32 + j];
        Wbt[t] = (f16)v;
    } else if (t < 17 * 32 * 32 + 3072) {
        int u = t - 17 * 32 * 32;
        Wihb[u] = (f16)Wih[u];
    } else if (t < 17 * 32 * 32 + 6144) {
        int u = t - 17 * 32 * 32 - 3072;
        Whhb[u] = (f16)Whh[u];
    }
}

// --------------------------- CSR build (once) ------------------------------
__global__ __launch_bounds__(256) void hist_kernel(
    const int* __restrict__ pair, int* __restrict__ cnt)
{
    int e = blockIdx.x * 256 + threadIdx.x;
    if (e < NE) atomicAdd(&cnt[reinterpret_cast<const int2*>(pair)[e].x], 1);
}

__global__ __launch_bounds__(1024) void scan1_kernel(
    const int* __restrict__ cnt, int* __restrict__ excl, int* __restrict__ bsum)
{
    __shared__ int tmp[1024];
    int g = blockIdx.x * 1024 + threadIdx.x;
    int v = (g < NA) ? cnt[g] : 0;
    tmp[threadIdx.x] = v;
    __syncthreads();
    for (int off = 1; off < 1024; off <<= 1) {
        int u = (threadIdx.x >= off) ? tmp[threadIdx.x - off] : 0;
        __syncthreads();
        tmp[threadIdx.x] += u;
        __syncthreads();
    }
    if (g < NA) excl[g] = tmp[threadIdx.x] - v;
    if (threadIdx.x == 1023) bsum[blockIdx.x] = tmp[1023];
}

__global__ __launch_bounds__(128) void scan2_kernel(int* __restrict__ bsum, int nb)
{
    __shared__ int tmp[128];
    int i = threadIdx.x;
    int v = (i < nb) ? bsum[i] : 0;
    tmp[i] = v;
    __syncthreads();
    for (int off = 1; off < 128; off <<= 1) {
        int u = (i >= off) ? tmp[i - off] : 0;
        __syncthreads();
        tmp[i] += u;
        __syncthreads();
    }
    if (i < nb) bsum[i] = tmp[i] - v;   // exclusive
}

__global__ __launch_bounds__(256) void scan3_kernel(
    const int* __restrict__ excl, const int* __restrict__ bsum,
    int* __restrict__ rowptr, int* __restrict__ next)
{
    int g = blockIdx.x * 256 + threadIdx.x;
    if (g < NA) {
        int v = excl[g] + bsum[g >> 10];
        rowptr[g] = v;
        next[g] = v;
    }
    if (g == NA) rowptr[NA] = NE;
}

// permute nbr + bond (fp32->fp16) into dst-sorted order
__global__ __launch_bounds__(256) void scatter_kernel(
    const float* __restrict__ bond, const int* __restrict__ pair,
    int* __restrict__ next, int* __restrict__ nbrp, f16* __restrict__ bondp)
{
    int e = blockIdx.x * 256 + threadIdx.x;
    if (e >= NE) return;
    int2 p = reinterpret_cast<const int2*>(pair)[e];
    int pos = atomicAdd(&next[p.x], 1);
    nbrp[pos] = p.y;
    const float4* b4 = reinterpret_cast<const float4*>(bond + (size_t)e * 16);
    float4 b0 = b4[0], b1 = b4[1], b2 = b4[2], b3 = b4[3];
    half8 o0, o1;
    o0[0]=(f16)b0.x; o0[1]=(f16)b0.y; o0[2]=(f16)b0.z; o0[3]=(f16)b0.w;
    o0[4]=(f16)b1.x; o0[5]=(f16)b1.y; o0[6]=(f16)b1.z; o0[7]=(f16)b1.w;
    o1[0]=(f16)b2.x; o1[1]=(f16)b2.y; o1[2]=(f16)b2.z; o1[3]=(f16)b2.w;
    o1[4]=(f16)b3.x; o1[5]=(f16)b3.y; o1[6]=(f16)b3.z; o1[7]=(f16)b3.w;
    half8* dst = reinterpret_cast<half8*>(bondp + (size_t)pos * 16);
    dst[0] = o0; dst[1] = o1;
}

// ---------------------------------------------------------------------------
// msg: persistent waves. W-fragments register-resident (34 x half8 = 136 VGPR,
// loaded once per wave), ~9 tiles per wave. Swapped operands (D = W*(c.h)):
// lane (col,kg) owns edge pos=tile*16+col, i = kg*4+r / 16+kg*4+r.
// Plain coalesced f16 stores to msg[pos] — ZERO atomics.
// ---------------------------------------------------------------------------
__global__ __launch_bounds__(256, 2) void msg_kernel(
    const f16* __restrict__ hb,              // [NA][32] fp16
    const f16* __restrict__ bondp,           // [NE][16] fp16 (sorted)
    const int* __restrict__ nbrp,            // [NE]       (sorted)
    const f16* __restrict__ Wbt,             // [17][32][32] fp16
    f16* __restrict__ msg)                   // [NE][32] fp16 (sorted)
{
    int wave = threadIdx.x >> 6;
    int lane = threadIdx.x & 63;
    int col  = lane & 15;
    int kg   = lane >> 4;

    // load all W fragments once (static-indexed -> registers)
    half8 w0[17], w1[17];
#pragma unroll
    for (int s = 0; s < 17; ++s) {
        w0[s] = *reinterpret_cast<const half8*>(Wbt + (s * 32 + col) * 32 + kg * 8);
        w1[s] = *reinterpret_cast<const half8*>(Wbt + (s * 32 + 16 + col) * 32 + kg * 8);
    }

    int wid = blockIdx.x * 4 + wave;
    int nw  = gridDim.x << 2;

    for (int tile = wid; tile < NTILES; tile += nw) {
        int pos = tile * 16 + col;
        int nbr = nbrp[pos];
        half8 hf = *reinterpret_cast<const half8*>(hb + (size_t)nbr * 32 + kg * 8);
        half8 cA = *reinterpret_cast<const half8*>(bondp + (size_t)pos * 16);
        half8 cB = *reinterpret_cast<const half8*>(bondp + (size_t)pos * 16 + 8);

        f32x4 acc0 = {0.f, 0.f, 0.f, 0.f};
        f32x4 acc1 = {0.f, 0.f, 0.f, 0.f};
#pragma unroll
        for (int s = 0; s < 16; ++s) {
            f16 ch = (s < 8) ? cA[s] : cB[s - 8];
            half8 a = hf * ch;               // v_pk_mul_f16 x4
            acc0 = __builtin_amdgcn_mfma_f32_16x16x32_f16(w0[s], a, acc0, 0, 0, 0);
            acc1 = __builtin_amdgcn_mfma_f32_16x16x32_f16(w1[s], a, acc1, 0, 0, 0);
        }
        acc0 = __builtin_amdgcn_mfma_f32_16x16x32_f16(w0[16], hf, acc0, 0, 0, 0);
        acc1 = __builtin_amdgcn_mfma_f32_16x16x32_f16(w1[16], hf, acc1, 0, 0, 0);

        half4 s0, s1;
        s0[0]=(f16)acc0[0]; s0[1]=(f16)acc0[1]; s0[2]=(f16)acc0[2]; s0[3]=(f16)acc0[3];
        s1[0]=(f16)acc1[0]; s1[1]=(f16)acc1[1]; s1[2]=(f16)acc1[2]; s1[3]=(f16)acc1[3];
        *reinterpret_cast<half4*>(msg + (size_t)pos * 32 + kg * 4)      = s0;
        *reinterpret_cast<half4*>(msg + (size_t)pos * 32 + 16 + kg * 4) = s1;
    }
}

// ---------------------------------------------------------------------------
// GRU via MFMA (fp16) with fused CSR segment-sum gather (no agg buffer,
// no atomics, no zeroing). fp32 hout written only at the final step.
// ---------------------------------------------------------------------------
__global__ __launch_bounds__(256) void gru_kernel(
    const f16* __restrict__ msg,              // [NE][32] fp16 (sorted)
    const int* __restrict__ rowptr,           // [NA+1]
    const f16* __restrict__ hb,               // [NA][32] fp16 (h_prev; rewritten)
    const f16* __restrict__ Wihb,             // [96][32] fp16
    const f16* __restrict__ Whhb,             // [96][32] fp16
    const float* __restrict__ bih, const float* __restrict__ bhh,
    float* __restrict__ hout, f16* __restrict__ hbf, int write_f32)
{
    int wave = threadIdx.x >> 6;
    int lane = threadIdx.x & 63;
    int tile = blockIdx.x * 4 + wave;
    if (tile >= ATILES) return;

    int base = tile * 16;
    int col  = lane & 15;
    int kg   = lane >> 4;
    int a0   = base + col;

    // segment-sum gather: agg[a0][kg*8 .. +8] in f32
    float xs[8] = {0.f, 0.f, 0.f, 0.f, 0.f, 0.f, 0.f, 0.f};
    int st = rowptr[a0], en = rowptr[a0 + 1];
    for (int p = st; p < en; ++p) {
        half8 m = *reinterpret_cast<const half8*>(msg + (size_t)p * 32 + kg * 8);
#pragma unroll
        for (int j = 0; j < 8; ++j) xs[j] += (float)m[j];
    }
    half8 xfrag;
#pragma unroll
    for (int j = 0; j < 8; ++j) xfrag[j] = (f16)xs[j];

    half8 hfrag = *reinterpret_cast<const half8*>(hb + (size_t)a0 * 32 + kg * 8);

    f32x4 gi[6], gh[6];
#pragma unroll
    for (int t = 0; t < 6; ++t) {
        half8 bi = *reinterpret_cast<const half8*>(Wihb + (size_t)(t * 16 + col) * 32 + kg * 8);
        half8 bh = *reinterpret_cast<const half8*>(Whhb + (size_t)(t * 16 + col) * 32 + kg * 8);
        f32x4 z = {0.f, 0.f, 0.f, 0.f};
        gi[t] = __builtin_amdgcn_mfma_f32_16x16x32_f16(xfrag, bi, z, 0, 0, 0);
        gh[t] = __builtin_amdgcn_mfma_f32_16x16x32_f16(hfrag, bh, z, 0, 0, 0);
    }

#pragma unroll
    for (int hh = 0; hh < 2; ++hh) {
        int i  = hh * 16 + col;
        float br  = bih[i]      + bhh[i];
        float bz  = bih[32 + i] + bhh[32 + i];
        float bin = bih[64 + i];
        float bhn = bhh[64 + i];
#pragma unroll
        for (int reg = 0; reg < 4; ++reg) {
            int a = base + kg * 4 + reg;
            float r = 1.f / (1.f + __expf(-(gi[hh][reg] + gh[hh][reg] + br)));
            float z = 1.f / (1.f + __expf(-(gi[2 + hh][reg] + gh[2 + hh][reg] + bz)));
            float n = tanhf(gi[4 + hh][reg] + bin + r * (gh[4 + hh][reg] + bhn));
            float hp = (float)hb[(size_t)a * 32 + i];
            float o  = (1.f - z) * n + z * hp;
            if (write_f32) hout[(size_t)a * 32 + i] = o;
            hbf[(size_t)a * 32 + i] = (f16)o;
        }
    }
}

extern "C" void kernel_launch(void* const* d_in, const int* in_sizes, int n_in,
                              void* d_out, int out_size, void* d_ws, size_t ws_size,
                              hipStream_t stream)
{
    const float* atom = (const float*)d_in[0];
    const float* bond = (const float*)d_in[1];
    const int*   pair = (const int*)  d_in[2];
    const float* Wb   = (const float*)d_in[3];
    const float* bb   = (const float*)d_in[4];
    const float* W_ih = (const float*)d_in[5];
    const float* W_hh = (const float*)d_in[6];
    const float* b_ih = (const float*)d_in[7];
    const float* b_hh = (const float*)d_in[8];
    float* out = (float*)d_out;

    char* w = (char*)d_ws;
    f16* msg    = (f16*)w;                       // 19,200,000 B
    f16* hbf    = (f16*)(w + 19200000);          //  6,400,000
    f16* bondp  = (f16*)(w + 25600000);          //  9,600,000
    f16* Wbt    = (f16*)(w + 35200000);          //     34,816
    f16* Wihb   = Wbt + 17 * 32 * 32;            //      6,144
    f16* Whhb   = Wihb + 96 * 32;                //      6,144
    int* rowcnt = (int*)(w + 35248000);          //    400,000
    int* excl   = (int*)(w + 35648000);          //    400,000
    int* bsum   = (int*)(w + 36048000);          //        512
    int* rowptr = (int*)(w + 36048512);          //    400,004
    int* next   = (int*)(w + 36448516);          //    400,000
    int* nbrp   = (int*)(w + 36848516);          //  1,200,000  (end ~38.0 MB)

    const int nsb = (NA + 1023) / 1024;          // 98 scan blocks

    // --- CSR build (once per launch) ---
    zero_kernel<<<(NA * 4 / 16 + 255) / 256, 256, 0, stream>>>((float4*)rowcnt, NA * 4 / 16);
    hist_kernel<<<(NE + 255) / 256, 256, 0, stream>>>(pair, rowcnt);
    scan1_kernel<<<nsb, 1024, 0, stream>>>(rowcnt, excl, bsum);
    scan2_kernel<<<1, 128, 0, stream>>>(bsum, nsb);
    scan3_kernel<<<(NA + 1 + 255) / 256, 256, 0, stream>>>(excl, bsum, rowptr, next);
    scatter_kernel<<<(NE + 255) / 256, 256, 0, stream>>>(bond, pair, next, nbrp, bondp);

    // --- weights + h to fp16 (once) ---
    prep_kernel<<<(17 * 32 * 32 + 6144 + 255) / 256, 256, 0, stream>>>(
        Wb, bb, W_ih, W_hh, Wbt, Wihb, Whhb);
    conv_kernel<<<(NA * 32 / 8 + 255) / 256, 256, 0, stream>>>(atom, hbf, NA * 32 / 8);

    const int gru_blocks = (ATILES + 3) / 4;
    for (int s = 0; s < STEPS; ++s) {
        msg_kernel<<<512, 256, 0, stream>>>(hbf, bondp, nbrp, Wbt, msg);
        gru_kernel<<<gru_blocks, 256, 0, stream>>>(msg, rowptr, hbf, Wihb, Whhb,
                                                   b_ih, b_hh, out, hbf,
                                                   (s == STEPS - 1) ? 1 : 0);
    }
}

// Round 11
// 200.420 us; speedup vs baseline: 1.8846x; 1.0474x over previous
//
#include <hip/hip_runtime.h>

#define NA 100000
#define NE 300000
#define STEPS 4
#define NTILES (NE / 16)        // 18750 (exact)
#define ATILES (NA / 16)        // 6250  (exact)

typedef _Float16 f16;
typedef _Float16 half8 __attribute__((ext_vector_type(8)));
using f32x4 = __attribute__((ext_vector_type(4))) float;

// ---------------------------------------------------------------------------
__global__ __launch_bounds__(256) void zero_kernel(float4* __restrict__ p, int n4)
{
    int t = blockIdx.x * 256 + threadIdx.x;
    if (t < n4) p[t] = make_float4(0.f, 0.f, 0.f, 0.f);
}

// fp32 -> fp16 bulk convert (step-0 h)
__global__ __launch_bounds__(256) void conv_kernel(
    const float* __restrict__ src, f16* __restrict__ dst, int n8)
{
    int t = blockIdx.x * 256 + threadIdx.x;
    if (t >= n8) return;
    float4 a = reinterpret_cast<const float4*>(src)[2 * t];
    float4 b = reinterpret_cast<const float4*>(src)[2 * t + 1];
    half8 o;
    o[0]=(f16)a.x; o[1]=(f16)a.y; o[2]=(f16)a.z; o[3]=(f16)a.w;
    o[4]=(f16)b.x; o[5]=(f16)b.y; o[6]=(f16)b.z; o[7]=(f16)b.w;
    reinterpret_cast<half8*>(dst)[t] = o;
}

// weights -> fp16. Wbt rows PERMUTED so lane(col,kg) emits i = kg*8..kg*8+7:
// block0 row m holds W-row i=(m>>2)*8+(m&3); block1 row m holds i=(m>>2)*8+4+(m&3).
__global__ __launch_bounds__(256) void prep_kernel(
    const float* __restrict__ Wb, const float* __restrict__ bb,
    const float* __restrict__ Wih, const float* __restrict__ Whh,
    f16* __restrict__ Wbt, f16* __restrict__ Wihb, f16* __restrict__ Whhb)
{
    int t = blockIdx.x * 256 + threadIdx.x;
    if (t < 17 * 32 * 32) {
        int j = t & 31, i = (t >> 5) & 31, k = t >> 10;
        float v = (k < 16) ? Wb[k * 1024 + i * 32 + j] : bb[i * 32 + j];
        int row = ((i & 4) ? 16 : 0) + ((i >> 3) << 2) + (i & 3);
        Wbt[(k * 32 + row) * 32 + j] = (f16)v;
    } else if (t < 17 * 32 * 32 + 3072) {
        int u = t - 17 * 32 * 32;
        Wihb[u] = (f16)Wih[u];
    } else if (t < 17 * 32 * 32 + 6144) {
        int u = t - 17 * 32 * 32 - 3072;
        Whhb[u] = (f16)Whh[u];
    }
}

// --------------------------- CSR build (once) ------------------------------
__global__ __launch_bounds__(256) void hist_kernel(
    const int* __restrict__ pair, int* __restrict__ cnt)
{
    int e = blockIdx.x * 256 + threadIdx.x;
    if (e < NE) atomicAdd(&cnt[reinterpret_cast<const int2*>(pair)[e].x], 1);
}

__global__ __launch_bounds__(1024) void scan1_kernel(
    const int* __restrict__ cnt, int* __restrict__ excl, int* __restrict__ bsum)
{
    __shared__ int tmp[1024];
    int g = blockIdx.x * 1024 + threadIdx.x;
    int v = (g < NA) ? cnt[g] : 0;
    tmp[threadIdx.x] = v;
    __syncthreads();
    for (int off = 1; off < 1024; off <<= 1) {
        int u = (threadIdx.x >= off) ? tmp[threadIdx.x - off] : 0;
        __syncthreads();
        tmp[threadIdx.x] += u;
        __syncthreads();
    }
    if (g < NA) excl[g] = tmp[threadIdx.x] - v;
    if (threadIdx.x == 1023) bsum[blockIdx.x] = tmp[1023];
}

__global__ __launch_bounds__(128) void scan2_kernel(int* __restrict__ bsum, int nb)
{
    __shared__ int tmp[128];
    int i = threadIdx.x;
    int v = (i < nb) ? bsum[i] : 0;
    tmp[i] = v;
    __syncthreads();
    for (int off = 1; off < 128; off <<= 1) {
        int u = (i >= off) ? tmp[i - off] : 0;
        __syncthreads();
        tmp[i] += u;
        __syncthreads();
    }
    if (i < nb) bsum[i] = tmp[i] - v;   // exclusive
}

__global__ __launch_bounds__(256) void scan3_kernel(
    const int* __restrict__ excl, const int* __restrict__ bsum,
    int* __restrict__ rowptr, int* __restrict__ next)
{
    int g = blockIdx.x * 256 + threadIdx.x;
    if (g < NA) {
        int v = excl[g] + bsum[g >> 10];
        rowptr[g] = v;
        next[g] = v;
    }
    if (g == NA) rowptr[NA] = NE;
}

// permute nbr + bond (fp32->fp16) into dst-sorted order
__global__ __launch_bounds__(256) void scatter_kernel(
    const float* __restrict__ bond, const int* __restrict__ pair,
    int* __restrict__ next, int* __restrict__ nbrp, f16* __restrict__ bondp)
{
    int e = blockIdx.x * 256 + threadIdx.x;
    if (e >= NE) return;
    int2 p = reinterpret_cast<const int2*>(pair)[e];
    int pos = atomicAdd(&next[p.x], 1);
    nbrp[pos] = p.y;
    const float4* b4 = reinterpret_cast<const float4*>(bond + (size_t)e * 16);
    float4 b0 = b4[0], b1 = b4[1], b2 = b4[2], b3 = b4[3];
    half8 o0, o1;
    o0[0]=(f16)b0.x; o0[1]=(f16)b0.y; o0[2]=(f16)b0.z; o0[3]=(f16)b0.w;
    o0[4]=(f16)b1.x; o0[5]=(f16)b1.y; o0[6]=(f16)b1.z; o0[7]=(f16)b1.w;
    o1[0]=(f16)b2.x; o1[1]=(f16)b2.y; o1[2]=(f16)b2.z; o1[3]=(f16)b2.w;
    o1[4]=(f16)b3.x; o1[5]=(f16)b3.y; o1[6]=(f16)b3.z; o1[7]=(f16)b3.w;
    half8* dst = reinterpret_cast<half8*>(bondp + (size_t)pos * 16);
    dst[0] = o0; dst[1] = o1;
}

// ---------------------------------------------------------------------------
// msg: persistent waves, W register-resident (34 x half8), 1-deep software
// pipeline: next tile's nbr/bond/hf loads issued before current tile's MFMAs.
// Output per lane = one contiguous half8 (i = kg*8..+7) -> single 16B store.
// ---------------------------------------------------------------------------
__global__ __launch_bounds__(256, 2) void msg_kernel(
    const f16* __restrict__ hb,              // [NA][32] fp16
    const f16* __restrict__ bondp,           // [NE][16] fp16 (sorted)
    const int* __restrict__ nbrp,            // [NE]       (sorted)
    const f16* __restrict__ Wbt,             // [17][32][32] fp16 (row-permuted)
    f16* __restrict__ msg)                   // [NE][32] fp16 (sorted)
{
    int wave = threadIdx.x >> 6;
    int lane = threadIdx.x & 63;
    int col  = lane & 15;
    int kg   = lane >> 4;

    half8 w0[17], w1[17];
#pragma unroll
    for (int s = 0; s < 17; ++s) {
        w0[s] = *reinterpret_cast<const half8*>(Wbt + (s * 32 + col) * 32 + kg * 8);
        w1[s] = *reinterpret_cast<const half8*>(Wbt + (s * 32 + 16 + col) * 32 + kg * 8);
    }

    int wid = blockIdx.x * 4 + wave;
    int nw  = gridDim.x << 2;

    int tile = wid;
    int pos = 0;
    half8 hf{}, cA{}, cB{};
    if (tile < NTILES) {
        pos = tile * 16 + col;
        int nbr = nbrp[pos];
        cA = *reinterpret_cast<const half8*>(bondp + (size_t)pos * 16);
        cB = *reinterpret_cast<const half8*>(bondp + (size_t)pos * 16 + 8);
        hf = *reinterpret_cast<const half8*>(hb + (size_t)nbr * 32 + kg * 8);
    }

    while (tile < NTILES) {
        // issue next tile's loads (hides gather latency under MFMAs below)
        int tile2 = tile + nw;
        int pos2 = 0;
        half8 hf2{}, cA2{}, cB2{};
        if (tile2 < NTILES) {
            pos2 = tile2 * 16 + col;
            int nbr2 = nbrp[pos2];
            cA2 = *reinterpret_cast<const half8*>(bondp + (size_t)pos2 * 16);
            cB2 = *reinterpret_cast<const half8*>(bondp + (size_t)pos2 * 16 + 8);
            hf2 = *reinterpret_cast<const half8*>(hb + (size_t)nbr2 * 32 + kg * 8);
        }

        f32x4 acc0 = {0.f, 0.f, 0.f, 0.f};
        f32x4 acc1 = {0.f, 0.f, 0.f, 0.f};
#pragma unroll
        for (int s = 0; s < 16; ++s) {
            f16 ch = (s < 8) ? cA[s] : cB[s - 8];
            half8 a = hf * ch;               // v_pk_mul_f16 x4
            acc0 = __builtin_amdgcn_mfma_f32_16x16x32_f16(w0[s], a, acc0, 0, 0, 0);
            acc1 = __builtin_amdgcn_mfma_f32_16x16x32_f16(w1[s], a, acc1, 0, 0, 0);
        }
        acc0 = __builtin_amdgcn_mfma_f32_16x16x32_f16(w0[16], hf, acc0, 0, 0, 0);
        acc1 = __builtin_amdgcn_mfma_f32_16x16x32_f16(w1[16], hf, acc1, 0, 0, 0);

        half8 so;   // i = kg*8 .. kg*8+7 (contiguous thanks to Wbt row permute)
        so[0]=(f16)acc0[0]; so[1]=(f16)acc0[1]; so[2]=(f16)acc0[2]; so[3]=(f16)acc0[3];
        so[4]=(f16)acc1[0]; so[5]=(f16)acc1[1]; so[6]=(f16)acc1[2]; so[7]=(f16)acc1[3];
        *reinterpret_cast<half8*>(msg + (size_t)pos * 32 + kg * 8) = so;

        tile = tile2; pos = pos2; hf = hf2; cA = cA2; cB = cB2;
    }
}

// ---------------------------------------------------------------------------
// GRU via MFMA (fp16), fused CSR segment-sum (gather unrolled x2).
// fp32 hout written only at the final step.
// ---------------------------------------------------------------------------
__global__ __launch_bounds__(256) void gru_kernel(
    const f16* __restrict__ msg,              // [NE][32] fp16 (sorted)
    const int* __restrict__ rowptr,           // [NA+1]
    const f16* __restrict__ hb,               // [NA][32] fp16 (h_prev; rewritten)
    const f16* __restrict__ Wihb,             // [96][32] fp16
    const f16* __restrict__ Whhb,             // [96][32] fp16
    const float* __restrict__ bih, const float* __restrict__ bhh,
    float* __restrict__ hout, f16* __restrict__ hbf, int write_f32)
{
    int wave = threadIdx.x >> 6;
    int lane = threadIdx.x & 63;
    int tile = blockIdx.x * 4 + wave;
    if (tile >= ATILES) return;

    int base = tile * 16;
    int col  = lane & 15;
    int kg   = lane >> 4;
    int a0   = base + col;

    float xs[8] = {0.f, 0.f, 0.f, 0.f, 0.f, 0.f, 0.f, 0.f};
    int st = rowptr[a0], en = rowptr[a0 + 1];
    int p = st;
    for (; p + 1 < en; p += 2) {
        half8 m0 = *reinterpret_cast<const half8*>(msg + (size_t)p * 32 + kg * 8);
        half8 m1 = *reinterpret_cast<const half8*>(msg + (size_t)(p + 1) * 32 + kg * 8);
#pragma unroll
        for (int j = 0; j < 8; ++j) xs[j] += (float)m0[j] + (float)m1[j];
    }
    if (p < en) {
        half8 m = *reinterpret_cast<const half8*>(msg + (size_t)p * 32 + kg * 8);
#pragma unroll
        for (int j = 0; j < 8; ++j) xs[j] += (float)m[j];
    }
    half8 xfrag;
#pragma unroll
    for (int j = 0; j < 8; ++j) xfrag[j] = (f16)xs[j];

    half8 hfrag = *reinterpret_cast<const half8*>(hb + (size_t)a0 * 32 + kg * 8);

    f32x4 gi[6], gh[6];
#pragma unroll
    for (int t = 0; t < 6; ++t) {
        half8 bi = *reinterpret_cast<const half8*>(Wihb + (size_t)(t * 16 + col) * 32 + kg * 8);
        half8 bh = *reinterpret_cast<const half8*>(Whhb + (size_t)(t * 16 + col) * 32 + kg * 8);
        f32x4 z = {0.f, 0.f, 0.f, 0.f};
        gi[t] = __builtin_amdgcn_mfma_f32_16x16x32_f16(xfrag, bi, z, 0, 0, 0);
        gh[t] = __builtin_amdgcn_mfma_f32_16x16x32_f16(hfrag, bh, z, 0, 0, 0);
    }

#pragma unroll
    for (int hh = 0; hh < 2; ++hh) {
        int i  = hh * 16 + col;
        float br  = bih[i]      + bhh[i];
        float bz  = bih[32 + i] + bhh[32 + i];
        float bin = bih[64 + i];
        float bhn = bhh[64 + i];
#pragma unroll
        for (int reg = 0; reg < 4; ++reg) {
            int a = base + kg * 4 + reg;
            float r = 1.f / (1.f + __expf(-(gi[hh][reg] + gh[hh][reg] + br)));
            float z = 1.f / (1.f + __expf(-(gi[2 + hh][reg] + gh[2 + hh][reg] + bz)));
            float n = tanhf(gi[4 + hh][reg] + bin + r * (gh[4 + hh][reg] + bhn));
            float hp = (float)hb[(size_t)a * 32 + i];
            float o  = (1.f - z) * n + z * hp;
            if (write_f32) hout[(size_t)a * 32 + i] = o;
            hbf[(size_t)a * 32 + i] = (f16)o;
        }
    }
}

extern "C" void kernel_launch(void* const* d_in, const int* in_sizes, int n_in,
                              void* d_out, int out_size, void* d_ws, size_t ws_size,
                              hipStream_t stream)
{
    const float* atom = (const float*)d_in[0];
    const float* bond = (const float*)d_in[1];
    const int*   pair = (const int*)  d_in[2];
    const float* Wb   = (const float*)d_in[3];
    const float* bb   = (const float*)d_in[4];
    const float* W_ih = (const float*)d_in[5];
    const float* W_hh = (const float*)d_in[6];
    const float* b_ih = (const float*)d_in[7];
    const float* b_hh = (const float*)d_in[8];
    float* out = (float*)d_out;

    char* w = (char*)d_ws;
    f16* msg    = (f16*)w;                       // 19,200,000 B
    f16* hbf    = (f16*)(w + 19200000);          //  6,400,000
    f16* bondp  = (f16*)(w + 25600000);          //  9,600,000
    f16* Wbt    = (f16*)(w + 35200000);          //     34,816
    f16* Wihb   = Wbt + 17 * 32 * 32;            //      6,144
    f16* Whhb   = Wihb + 96 * 32;                //      6,144
    int* rowcnt = (int*)(w + 35248000);          //    400,000
    int* excl   = (int*)(w + 35648000);          //    400,000
    int* bsum   = (int*)(w + 36048000);          //        512
    int* rowptr = (int*)(w + 36048512);          //    400,004
    int* next   = (int*)(w + 36448516);          //    400,000
    int* nbrp   = (int*)(w + 36848516);          //  1,200,000  (end ~38.0 MB)

    const int nsb = (NA + 1023) / 1024;          // 98 scan blocks

    // --- CSR build (once per launch) ---
    zero_kernel<<<(NA * 4 / 16 + 255) / 256, 256, 0, stream>>>((float4*)rowcnt, NA * 4 / 16);
    hist_kernel<<<(NE + 255) / 256, 256, 0, stream>>>(pair, rowcnt);
    scan1_kernel<<<nsb, 1024, 0, stream>>>(rowcnt, excl, bsum);
    scan2_kernel<<<1, 128, 0, stream>>>(bsum, nsb);
    scan3_kernel<<<(NA + 1 + 255) / 256, 256, 0, stream>>>(excl, bsum, rowptr, next);
    scatter_kernel<<<(NE + 255) / 256, 256, 0, stream>>>(bond, pair, next, nbrp, bondp);

    // --- weights + h to fp16 (once) ---
    prep_kernel<<<(17 * 32 * 32 + 6144 + 255) / 256, 256, 0, stream>>>(
        Wb, bb, W_ih, W_hh, Wbt, Wihb, Whhb);
    conv_kernel<<<(NA * 32 / 8 + 255) / 256, 256, 0, stream>>>(atom, hbf, NA * 32 / 8);

    const int gru_blocks = (ATILES + 3) / 4;
    for (int s = 0; s < STEPS; ++s) {
        msg_kernel<<<512, 256, 0, stream>>>(hbf, bondp, nbrp, Wbt, msg);
        gru_kernel<<<gru_blocks, 256, 0, stream>>>(msg, rowptr, hbf, Wihb, Whhb,
                                                   b_ih, b_hh, out, hbf,
                                                   (s == STEPS - 1) ? 1 : 0);
    }
}